// Round 2
// baseline (354.799 us; speedup 1.0000x reference)
//
#include <hip/hip_runtime.h>

#define Bn 128
#define Hn 28
#define Wn 28
#define Cn 512
#define Pn (Hn * Wn)      // 784 spatial positions
#define SCH 8             // spatial chunks for argmax parallelism
#define PCH (Pn / SCH)    // 98 positions per chunk

// ---------------------------------------------------------------------------
// Kernel 1a: partial spatial argmax per (b, c) over one chunk of 98 positions.
// Grid: Bn * 2 * SCH blocks of 256 threads (thread = one c within half of C).
// Lanes map to consecutive c -> every load is a coalesced 1KB/block segment.
// Partials stored [s][b][c] so both this write and the combiner read coalesce.
// ---------------------------------------------------------------------------
__global__ void argmax_partial(const float* __restrict__ x,
                               uint2* __restrict__ part) {
    int blk = blockIdx.x;
    int s = blk & (SCH - 1);         // spatial chunk
    int rest = blk >> 3;
    int cchunk = rest & 1;
    int b = rest >> 1;
    int c = cchunk * 256 + threadIdx.x;

    const float* xp = x + (size_t)b * Pn * Cn + c;
    int p0 = s * PCH;

    float best = -INFINITY;
    int bi = p0;
#pragma unroll 7
    for (int i = 0; i < PCH; ++i) {
        float v = xp[(size_t)(p0 + i) * Cn];
        if (v > best) { best = v; bi = p0 + i; }
    }
    uint2 r;
    r.x = __float_as_uint(best);
    r.y = (unsigned)bi;
    part[(size_t)s * (Bn * Cn) + (size_t)b * Cn + c] = r;
}

// ---------------------------------------------------------------------------
// Kernel 1b: combine 8 chunk partials per (b,c). Sequential strict-> in chunk
// order preserves np.argmax first-max tie-breaking.
// ---------------------------------------------------------------------------
__global__ void argmax_combine(const uint2* __restrict__ part,
                               int* __restrict__ idx) {
    int bc = blockIdx.x * 256 + threadIdx.x;   // 0 .. B*C-1
    float best = -INFINITY;
    int bi = 0;
#pragma unroll
    for (int s = 0; s < SCH; ++s) {
        uint2 r = part[(size_t)s * (Bn * Cn) + bc];
        float v = __uint_as_float(r.x);
        if (v > best) { best = v; bi = (int)r.y; }
    }
    idx[bc] = bi;
}

// ---------------------------------------------------------------------------
// Kernel 2: elementwise output pass, float4 over consecutive c.
//   t = t_p[idx[b,c]*784 + p];  o0 = relu(x*t);  o1 = x;  o2 = t
// t_p is 2.4 MB -> L2-resident gather. All global loads/stores coalesced.
// ---------------------------------------------------------------------------
__global__ void write_outputs(const float* __restrict__ x,
                              const float* __restrict__ tp,
                              const int* __restrict__ idx,
                              float* __restrict__ o0,
                              float* __restrict__ o1,
                              float* __restrict__ o2) {
    size_t i = ((size_t)blockIdx.x * blockDim.x + threadIdx.x) * 4;
    int c4 = (int)(i & (Cn - 1));      // i % 512 (multiple of 4)
    size_t bp = i >> 9;                // i / 512
    int b = (int)(bp / Pn);
    int p = (int)(bp % Pn);

    float4 xv = *reinterpret_cast<const float4*>(x + i);
    int4 iv = *reinterpret_cast<const int4*>(idx + (size_t)b * Cn + c4);

    float t0 = tp[(size_t)iv.x * Pn + p];
    float t1 = tp[(size_t)iv.y * Pn + p];
    float t2 = tp[(size_t)iv.z * Pn + p];
    float t3 = tp[(size_t)iv.w * Pn + p];

    float4 tv = make_float4(t0, t1, t2, t3);
    float4 mv = make_float4(fmaxf(xv.x * t0, 0.f),
                            fmaxf(xv.y * t1, 0.f),
                            fmaxf(xv.z * t2, 0.f),
                            fmaxf(xv.w * t3, 0.f));

    *reinterpret_cast<float4*>(o0 + i) = mv;
    *reinterpret_cast<float4*>(o1 + i) = xv;
    *reinterpret_cast<float4*>(o2 + i) = tv;
}

extern "C" void kernel_launch(void* const* d_in, const int* in_sizes, int n_in,
                              void* d_out, int out_size, void* d_ws, size_t ws_size,
                              hipStream_t stream) {
    const float* x  = (const float*)d_in[0];   // [B,H,W,C] fp32
    const float* tp = (const float*)d_in[1];   // [H,W,H,W] fp32

    const size_t N = (size_t)Bn * Pn * Cn;     // 51,380,224 elements per output
    float* o0 = (float*)d_out;                 // masked
    float* o1 = o0 + N;                        // x copy
    float* o2 = o0 + 2 * N;                    // templates

    // Workspace layout: [SCH][B][C] uint2 partials (4 MiB), then int idx[B*C].
    uint2* part = (uint2*)d_ws;
    int* idx = (int*)((char*)d_ws + (size_t)SCH * Bn * Cn * sizeof(uint2));

    argmax_partial<<<Bn * 2 * SCH, 256, 0, stream>>>(x, part);
    argmax_combine<<<(Bn * Cn) / 256, 256, 0, stream>>>(part, idx);
    write_outputs<<<(unsigned)(N / 4 / 256), 256, 0, stream>>>(x, tp, idx, o0, o1, o2);
}

// Round 3
// 286.405 us; speedup vs baseline: 1.2388x; 1.2388x over previous
//
#include <hip/hip_runtime.h>

#define Bn 128
#define Hn 28
#define Wn 28
#define Cn 512
#define Pn (Hn * Wn)      // 784 spatial positions
#define SCH 8             // spatial chunks for argmax parallelism
#define PCH (Pn / SCH)    // 98 positions per chunk
#define PPB 56            // p per block in write_outputs (784 = 14*56)
#define PPT 28            // p per thread (half-block)

// ---------------------------------------------------------------------------
// Kernel 1a: partial spatial argmax per (b, c) over one chunk of 98 positions.
// Thread owns 4 consecutive c -> float4 loads, 1KB/wave-instr fully coalesced.
// Grid: Bn*SCH blocks of 128 threads. Partials stored [s][b][c] (uint2).
// ---------------------------------------------------------------------------
__global__ void argmax_partial(const float* __restrict__ x,
                               uint2* __restrict__ part) {
    int s = blockIdx.x & (SCH - 1);
    int b = blockIdx.x >> 3;
    int c0 = threadIdx.x * 4;

    const float* xp = x + (size_t)b * Pn * Cn + c0;
    int p0 = s * PCH;

    float b0 = -INFINITY, b1 = -INFINITY, b2 = -INFINITY, b3 = -INFINITY;
    int i0 = p0, i1 = p0, i2 = p0, i3 = p0;
#pragma unroll 7
    for (int i = 0; i < PCH; ++i) {
        float4 v = *reinterpret_cast<const float4*>(xp + (size_t)(p0 + i) * Cn);
        if (v.x > b0) { b0 = v.x; i0 = p0 + i; }
        if (v.y > b1) { b1 = v.y; i1 = p0 + i; }
        if (v.z > b2) { b2 = v.z; i2 = p0 + i; }
        if (v.w > b3) { b3 = v.w; i3 = p0 + i; }
    }
    uint2* o = part + (size_t)s * (Bn * Cn) + (size_t)b * Cn + c0;
    o[0] = make_uint2(__float_as_uint(b0), (unsigned)i0);
    o[1] = make_uint2(__float_as_uint(b1), (unsigned)i1);
    o[2] = make_uint2(__float_as_uint(b2), (unsigned)i2);
    o[3] = make_uint2(__float_as_uint(b3), (unsigned)i3);
}

// ---------------------------------------------------------------------------
// Kernel 1b: combine 8 chunk partials per (b,c). Sequential strict-> in chunk
// order preserves np.argmax first-max tie-breaking.
// ---------------------------------------------------------------------------
__global__ void argmax_combine(const uint2* __restrict__ part,
                               int* __restrict__ idx) {
    int bc = blockIdx.x * 256 + threadIdx.x;
    float best = -INFINITY;
    int bi = 0;
#pragma unroll
    for (int s = 0; s < SCH; ++s) {
        uint2 r = part[(size_t)s * (Bn * Cn) + bc];
        float v = __uint_as_float(r.x);
        if (v > best) { best = v; bi = (int)r.y; }
    }
    idx[bc] = bi;
}

// ---------------------------------------------------------------------------
// Kernel 2: elementwise output pass.
// Thread owns 4 consecutive c and a 28-p range: its 4 template rows are read
// with sequential float4 loads (full L2-line utilization, per-lane streaming);
// x loads and all stores are float4, 1KB/wave-instr coalesced.
// Block 256 = 128 c-threads x 2 p-halves; grid = B * 14 p-chunks.
// ---------------------------------------------------------------------------
__global__ void write_outputs(const float* __restrict__ x,
                              const float* __restrict__ tp,
                              const int* __restrict__ idx,
                              float* __restrict__ o0,
                              float* __restrict__ o1,
                              float* __restrict__ o2) {
    int pc = blockIdx.x % 14;
    int b  = blockIdx.x / 14;
    int ci = threadIdx.x & 127;
    int c0 = ci * 4;
    int ph = threadIdx.x >> 7;
    int p0 = pc * PPB + ph * PPT;

    int4 iv = *reinterpret_cast<const int4*>(idx + (size_t)b * Cn + c0);
    const float* t0p = tp + (size_t)iv.x * Pn;
    const float* t1p = tp + (size_t)iv.y * Pn;
    const float* t2p = tp + (size_t)iv.z * Pn;
    const float* t3p = tp + (size_t)iv.w * Pn;

    size_t xbase = (size_t)b * Pn * Cn + c0;

#pragma unroll
    for (int j = 0; j < PPT; j += 4) {
        int p = p0 + j;
        // 4 template rows, 4 consecutive p each (per-lane sequential float4)
        float4 ta = *reinterpret_cast<const float4*>(t0p + p);
        float4 tb = *reinterpret_cast<const float4*>(t1p + p);
        float4 tc = *reinterpret_cast<const float4*>(t2p + p);
        float4 td = *reinterpret_cast<const float4*>(t3p + p);
        float4 x0 = *reinterpret_cast<const float4*>(x + xbase + (size_t)(p + 0) * Cn);
        float4 x1 = *reinterpret_cast<const float4*>(x + xbase + (size_t)(p + 1) * Cn);
        float4 x2 = *reinterpret_cast<const float4*>(x + xbase + (size_t)(p + 2) * Cn);
        float4 x3 = *reinterpret_cast<const float4*>(x + xbase + (size_t)(p + 3) * Cn);

        // transpose: tv_q = template values for position p+q across the 4 c's
        float4 tv0 = make_float4(ta.x, tb.x, tc.x, td.x);
        float4 tv1 = make_float4(ta.y, tb.y, tc.y, td.y);
        float4 tv2 = make_float4(ta.z, tb.z, tc.z, td.z);
        float4 tv3 = make_float4(ta.w, tb.w, tc.w, td.w);

        float4 m0 = make_float4(fmaxf(x0.x * tv0.x, 0.f), fmaxf(x0.y * tv0.y, 0.f),
                                fmaxf(x0.z * tv0.z, 0.f), fmaxf(x0.w * tv0.w, 0.f));
        float4 m1 = make_float4(fmaxf(x1.x * tv1.x, 0.f), fmaxf(x1.y * tv1.y, 0.f),
                                fmaxf(x1.z * tv1.z, 0.f), fmaxf(x1.w * tv1.w, 0.f));
        float4 m2 = make_float4(fmaxf(x2.x * tv2.x, 0.f), fmaxf(x2.y * tv2.y, 0.f),
                                fmaxf(x2.z * tv2.z, 0.f), fmaxf(x2.w * tv2.w, 0.f));
        float4 m3 = make_float4(fmaxf(x3.x * tv3.x, 0.f), fmaxf(x3.y * tv3.y, 0.f),
                                fmaxf(x3.z * tv3.z, 0.f), fmaxf(x3.w * tv3.w, 0.f));

        size_t q0 = xbase + (size_t)(p + 0) * Cn;
        size_t q1 = xbase + (size_t)(p + 1) * Cn;
        size_t q2 = xbase + (size_t)(p + 2) * Cn;
        size_t q3 = xbase + (size_t)(p + 3) * Cn;
        *reinterpret_cast<float4*>(o0 + q0) = m0;
        *reinterpret_cast<float4*>(o0 + q1) = m1;
        *reinterpret_cast<float4*>(o0 + q2) = m2;
        *reinterpret_cast<float4*>(o0 + q3) = m3;
        *reinterpret_cast<float4*>(o1 + q0) = x0;
        *reinterpret_cast<float4*>(o1 + q1) = x1;
        *reinterpret_cast<float4*>(o1 + q2) = x2;
        *reinterpret_cast<float4*>(o1 + q3) = x3;
        *reinterpret_cast<float4*>(o2 + q0) = tv0;
        *reinterpret_cast<float4*>(o2 + q1) = tv1;
        *reinterpret_cast<float4*>(o2 + q2) = tv2;
        *reinterpret_cast<float4*>(o2 + q3) = tv3;
    }
}

extern "C" void kernel_launch(void* const* d_in, const int* in_sizes, int n_in,
                              void* d_out, int out_size, void* d_ws, size_t ws_size,
                              hipStream_t stream) {
    const float* x  = (const float*)d_in[0];   // [B,H,W,C] fp32
    const float* tp = (const float*)d_in[1];   // [H,W,H,W] fp32

    const size_t N = (size_t)Bn * Pn * Cn;
    float* o0 = (float*)d_out;                 // masked
    float* o1 = o0 + N;                        // x copy
    float* o2 = o0 + 2 * N;                    // templates

    uint2* part = (uint2*)d_ws;
    int* idx = (int*)((char*)d_ws + (size_t)SCH * Bn * Cn * sizeof(uint2));

    argmax_partial<<<Bn * SCH, 128, 0, stream>>>(x, part);
    argmax_combine<<<(Bn * Cn) / 256, 256, 0, stream>>>(part, idx);
    write_outputs<<<Bn * 14, 256, 0, stream>>>(x, tp, idx, o0, o1, o2);
}

// Round 5
// 160.577 us; speedup vs baseline: 2.2095x; 1.7836x over previous
//
#include <hip/hip_runtime.h>

#define Bn 128
#define Hn 28
#define Wn 28
#define Cn 512
#define Pn (Hn * Wn)      // 784 spatial positions
#define SCH 8             // spatial chunks for argmax parallelism
#define PCH (Pn / SCH)    // 98 positions per chunk
#define PPB 56            // p per block in mask kernel (784 = 14*56)
#define PPT 28            // p per thread (half-block)

// Native vector type for __builtin_nontemporal_store (HIP's float4 class is
// rejected by the builtin; this alias is layout-identical).
typedef float f4 __attribute__((ext_vector_type(4)));

__device__ __forceinline__ void nt_store4(float* p, float a, float b, float c, float d) {
    f4 v = {a, b, c, d};
    __builtin_nontemporal_store(v, reinterpret_cast<f4*>(p));
}

// ---------------------------------------------------------------------------
// Kernel 1: partial spatial argmax per (b,c) over one 98-p chunk, FUSED with
// the o1 = x copy (we already read every element; the store is free BW-wise).
// Output stores are non-temporal so they don't evict x from L3 -- kernel 3
// re-reads x and we want those to be LLC hits.
// Thread owns 4 consecutive c -> float4, 1KB/wave-instr coalesced.
// ---------------------------------------------------------------------------
__global__ void argmax_partial_copy(const float* __restrict__ x,
                                    float* __restrict__ o1,
                                    uint2* __restrict__ part) {
    int s = blockIdx.x & (SCH - 1);
    int b = blockIdx.x >> 3;
    int c0 = threadIdx.x * 4;

    size_t base = (size_t)b * Pn * Cn + c0;
    int p0 = s * PCH;

    float b0 = -INFINITY, b1 = -INFINITY, b2 = -INFINITY, b3 = -INFINITY;
    int i0 = p0, i1 = p0, i2 = p0, i3 = p0;
#pragma unroll 7
    for (int i = 0; i < PCH; ++i) {
        size_t off = base + (size_t)(p0 + i) * Cn;
        float4 v = *reinterpret_cast<const float4*>(x + off);
        nt_store4(o1 + off, v.x, v.y, v.z, v.w);
        if (v.x > b0) { b0 = v.x; i0 = p0 + i; }
        if (v.y > b1) { b1 = v.y; i1 = p0 + i; }
        if (v.z > b2) { b2 = v.z; i2 = p0 + i; }
        if (v.w > b3) { b3 = v.w; i3 = p0 + i; }
    }
    uint2* o = part + (size_t)s * (Bn * Cn) + (size_t)b * Cn + c0;
    o[0] = make_uint2(__float_as_uint(b0), (unsigned)i0);
    o[1] = make_uint2(__float_as_uint(b1), (unsigned)i1);
    o[2] = make_uint2(__float_as_uint(b2), (unsigned)i2);
    o[3] = make_uint2(__float_as_uint(b3), (unsigned)i3);
}

// ---------------------------------------------------------------------------
// Kernel 2: combine 8 chunk partials per (b,c). Sequential strict-> in chunk
// order preserves np.argmax first-max tie-breaking.
// ---------------------------------------------------------------------------
__global__ void argmax_combine(const uint2* __restrict__ part,
                               int* __restrict__ idx) {
    int bc = blockIdx.x * 256 + threadIdx.x;
    float best = -INFINITY;
    int bi = 0;
#pragma unroll
    for (int s = 0; s < SCH; ++s) {
        uint2 r = part[(size_t)s * (Bn * Cn) + bc];
        float v = __uint_as_float(r.x);
        if (v > best) { best = v; bi = (int)r.y; }
    }
    idx[bc] = bi;
}

// ---------------------------------------------------------------------------
// Kernel 3: mask pass -- o0 = relu(x*t), o2 = t. Streams: x read (mostly
// L3-resident from kernel 1), t_p gather (L2-resident, per-lane sequential
// float4), two non-temporal write streams.
// Thread owns 4 consecutive c and a 28-p range. Block 256 = 128 c-threads x 2
// p-halves; grid = B * 14 p-chunks.
// ---------------------------------------------------------------------------
__global__ void mask_outputs(const float* __restrict__ x,
                             const float* __restrict__ tp,
                             const int* __restrict__ idx,
                             float* __restrict__ o0,
                             float* __restrict__ o2) {
    int pc = blockIdx.x % 14;
    int b  = blockIdx.x / 14;
    int ci = threadIdx.x & 127;
    int c0 = ci * 4;
    int ph = threadIdx.x >> 7;
    int p0 = pc * PPB + ph * PPT;

    int4 iv = *reinterpret_cast<const int4*>(idx + (size_t)b * Cn + c0);
    const float* t0p = tp + (size_t)iv.x * Pn;
    const float* t1p = tp + (size_t)iv.y * Pn;
    const float* t2p = tp + (size_t)iv.z * Pn;
    const float* t3p = tp + (size_t)iv.w * Pn;

    size_t xbase = (size_t)b * Pn * Cn + c0;

#pragma unroll
    for (int j = 0; j < PPT; j += 4) {
        int p = p0 + j;
        float4 ta = *reinterpret_cast<const float4*>(t0p + p);
        float4 tb = *reinterpret_cast<const float4*>(t1p + p);
        float4 tc = *reinterpret_cast<const float4*>(t2p + p);
        float4 td = *reinterpret_cast<const float4*>(t3p + p);
        float4 x0 = *reinterpret_cast<const float4*>(x + xbase + (size_t)(p + 0) * Cn);
        float4 x1 = *reinterpret_cast<const float4*>(x + xbase + (size_t)(p + 1) * Cn);
        float4 x2 = *reinterpret_cast<const float4*>(x + xbase + (size_t)(p + 2) * Cn);
        float4 x3 = *reinterpret_cast<const float4*>(x + xbase + (size_t)(p + 3) * Cn);

        size_t q0 = xbase + (size_t)(p + 0) * Cn;
        size_t q1 = xbase + (size_t)(p + 1) * Cn;
        size_t q2 = xbase + (size_t)(p + 2) * Cn;
        size_t q3 = xbase + (size_t)(p + 3) * Cn;

        nt_store4(o0 + q0, fmaxf(x0.x * ta.x, 0.f), fmaxf(x0.y * tb.x, 0.f),
                           fmaxf(x0.z * tc.x, 0.f), fmaxf(x0.w * td.x, 0.f));
        nt_store4(o0 + q1, fmaxf(x1.x * ta.y, 0.f), fmaxf(x1.y * tb.y, 0.f),
                           fmaxf(x1.z * tc.y, 0.f), fmaxf(x1.w * td.y, 0.f));
        nt_store4(o0 + q2, fmaxf(x2.x * ta.z, 0.f), fmaxf(x2.y * tb.z, 0.f),
                           fmaxf(x2.z * tc.z, 0.f), fmaxf(x2.w * td.z, 0.f));
        nt_store4(o0 + q3, fmaxf(x3.x * ta.w, 0.f), fmaxf(x3.y * tb.w, 0.f),
                           fmaxf(x3.z * tc.w, 0.f), fmaxf(x3.w * td.w, 0.f));
        nt_store4(o2 + q0, ta.x, tb.x, tc.x, td.x);
        nt_store4(o2 + q1, ta.y, tb.y, tc.y, td.y);
        nt_store4(o2 + q2, ta.z, tb.z, tc.z, td.z);
        nt_store4(o2 + q3, ta.w, tb.w, tc.w, td.w);
    }
}

extern "C" void kernel_launch(void* const* d_in, const int* in_sizes, int n_in,
                              void* d_out, int out_size, void* d_ws, size_t ws_size,
                              hipStream_t stream) {
    const float* x  = (const float*)d_in[0];   // [B,H,W,C] fp32
    const float* tp = (const float*)d_in[1];   // [H,W,H,W] fp32

    const size_t N = (size_t)Bn * Pn * Cn;
    float* o0 = (float*)d_out;                 // masked
    float* o1 = o0 + N;                        // x copy
    float* o2 = o0 + 2 * N;                    // templates

    uint2* part = (uint2*)d_ws;
    int* idx = (int*)((char*)d_ws + (size_t)SCH * Bn * Cn * sizeof(uint2));

    argmax_partial_copy<<<Bn * SCH, 128, 0, stream>>>(x, o1, part);
    argmax_combine<<<(Bn * Cn) / 256, 256, 0, stream>>>(part, idx);
    mask_outputs<<<Bn * 14, 256, 0, stream>>>(x, tp, idx, o0, o2);
}